// Round 17
// baseline (67.779 us; speedup 1.0000x reference)
//
#include <hip/hip_runtime.h>
#include <hip/hip_bf16.h>
#include <string.h>

typedef __attribute__((ext_vector_type(8))) short short8;
typedef __attribute__((ext_vector_type(16))) float f32x16;

// packed f32x2 -> bf16x2 via v_cvt_pk_bf16_f32 (1 VALU op vs ~6 for the
// scalar cvt+shift+or chain). lo -> low 16 bits, hi -> high 16 bits.
// (__hip_bfloat162 is not trivially copyable -> extract via memcpy, which
// clang folds to a register move at -O3; R16 failed on __builtin_bit_cast.)
__device__ __forceinline__ unsigned pk2(float lo, float hi) {
  float2 t; t.x = lo; t.y = hi;
  __hip_bfloat162 b2 = __float22bfloat162_rn(t);
  unsigned u;
  memcpy(&u, &b2, 4);
  return u;
}

__device__ __forceinline__ short8 lds_read16(const short* p, int byteOff) {
  return *reinterpret_cast<const short8*>(reinterpret_cast<const char*>(p) + byteOff);
}

#define MFMA(a, b, c) __builtin_amdgcn_mfma_f32_32x32x16_bf16((a), (b), (c), 0, 0, 0)

// x:[524288][64] f32, w1:[8][64][256] f32, w2:[8][256][64] f32, out = x shape.
// Grid 512 x 768 threads. expert = blockIdx&7 (XCD-pinned), chunk =
// blockIdx>>3 in 0..63 owns 1024 rows = 32 tiles of 32 rows.
// Tile split across 12 waves: wv<8 -> 3 tiles, wv>=8 -> 2 tiles.
//
// Measured trail: R11 16w/CU=67.5us -> R15 24w/CU=65.8us: TLP saturated.
// All pipes <=26%; VALU is the largest (26%). R17 (=R16 fixed): packed
// cvt_pk_bf16_f32 for ALL f32->bf16 pairs (x-convert, relu-pack, staging)
// -- targets the top counter and shortens the h->pack->exchange chain.
// Geometry/layout/exchange identical to R15 (proven).
//
// LDS layouts (R13, conflict-free, addr = base + induction offset):
//   w1t chunk(c=ks*2+g, f):  byte c*4096 + f*16 = W1^T[f][d=8c..8c+7]
//   w2t chunk(c2=ks2*2+g,d): byte c2*1024 + d*16 = W2^T[d][f=8c2..8c2+7]
__launch_bounds__(768, 2)
__global__ void ffn_fused(const float* __restrict__ x,
                          const float* __restrict__ w1,
                          const float* __restrict__ w2,
                          float* __restrict__ out) {
  __shared__ short w1t[4 * 2 * 256 * 8];   // 32 KB
  __shared__ short w2t[16 * 2 * 64 * 8];   // 32 KB

  const int tid  = threadIdx.x;
  const int lane = tid & 63;
  const int wv   = tid >> 6;   // wave 0..11
  const int m    = lane & 31;
  const int g    = lane >> 5;

  const int e     = blockIdx.x & 7;   // expert -> XCD pinned (weights L2-hot)
  const int chunk = blockIdx.x >> 3;  // 0..63

  const float* W1 = w1 + e * (64 * 256);
  const float* W2 = w2 + e * (256 * 64);

  // ---- stage W1 chunks (threads 0..511 only) ----
  if (tid < 512) {
    const int f  = tid & 255;
    const int cb = (tid >> 8) * 4;
#pragma unroll 2
    for (int ci = 0; ci < 4; ++ci) {
      const int c  = cb + ci;     // c = ks*2+g
      const int d0 = c * 8;
      float a0 = W1[(d0 + 0) * 256 + f], a1 = W1[(d0 + 1) * 256 + f];
      float a2 = W1[(d0 + 2) * 256 + f], a3 = W1[(d0 + 3) * 256 + f];
      float a4 = W1[(d0 + 4) * 256 + f], a5 = W1[(d0 + 5) * 256 + f];
      float a6 = W1[(d0 + 6) * 256 + f], a7 = W1[(d0 + 7) * 256 + f];
      *reinterpret_cast<uint4*>(reinterpret_cast<char*>(w1t) + c * 4096 + f * 16) =
          make_uint4(pk2(a0, a1), pk2(a2, a3), pk2(a4, a5), pk2(a6, a7));
    }
  }
  // ---- stage W2 chunks: d = tid&63, group r = tid>>6 in 0..11 ----
  {
    const int d = tid & 63;
    const int r = tid >> 6;
#pragma unroll 1
    for (int ci = 0; ci < 3; ++ci) {
      const int c2 = r + 12 * ci;  // r<8: 3 chunks; r>=8: 2 chunks
      if (c2 < 32) {
        const int f0 = c2 * 8;
        float a0 = W2[(f0 + 0) * 64 + d], a1 = W2[(f0 + 1) * 64 + d];
        float a2 = W2[(f0 + 2) * 64 + d], a3 = W2[(f0 + 3) * 64 + d];
        float a4 = W2[(f0 + 4) * 64 + d], a5 = W2[(f0 + 5) * 64 + d];
        float a6 = W2[(f0 + 6) * 64 + d], a7 = W2[(f0 + 7) * 64 + d];
        *reinterpret_cast<uint4*>(reinterpret_cast<char*>(w2t) + c2 * 1024 + d * 16) =
            make_uint4(pk2(a0, a1), pk2(a2, a3), pk2(a4, a5), pk2(a6, a7));
      }
    }
  }
  __syncthreads();  // only barrier in the kernel

  // tile range for this wave: wv<8 -> 3 tiles, wv>=8 -> 2 tiles (32 total)
  const int t0 = (wv < 8) ? 3 * wv : 24 + 2 * (wv - 8);
  const int t1 = (wv < 8) ? t0 + 3 : t0 + 2;

  const long rowBase = (long)e * 65536 + (long)chunk * 1024;

  // per-lane LDS read bases; all per-read variation is immediate/induction
  const int baseA = g * 4096 + m * 16;  // + ks*8192 + ft*512
  const int baseW = g * 1024 + m * 16;  // + ks2*2048 (+512 for d+32 row)

#pragma unroll 1
  for (int it = t0; it < t1; ++it) {
    const long rb = rowBase + it * 32;  // this wave's 32 rows this tile

    // ---- load + convert x fragments (cvt_pk: 2 floats -> 1 word) ----
    short8 xf[4];
#pragma unroll
    for (int ks = 0; ks < 4; ++ks) {
      const float* px = x + (rb + m) * 64 + ks * 16 + g * 8;
      const float4 u0 = *reinterpret_cast<const float4*>(px);
      const float4 u1 = *reinterpret_cast<const float4*>(px + 4);
      union { short8 v; unsigned u[4]; } t;
      t.u[0] = pk2(u0.x, u0.y);
      t.u[1] = pk2(u0.z, u0.w);
      t.u[2] = pk2(u1.x, u1.y);
      t.u[3] = pk2(u1.z, u1.w);
      xf[ks] = t.v;
    }

    f32x16 o0, o1;  // out^T acc per dt half
#pragma unroll
    for (int i = 0; i < 16; ++i) { o0[i] = 0.f; o1[i] = 0.f; }

#pragma unroll 1
    for (int ft = 0; ft < 8; ++ft) {
      // GEMM1: h^T tile [32f x 32m]; a-reads lane-contiguous, addr = base+imm
      short8 a[4];
#pragma unroll
      for (int ks = 0; ks < 4; ++ks)
        a[ks] = lds_read16(w1t, baseA + ks * 8192 + ft * 512);

      f32x16 h;
#pragma unroll
      for (int i = 0; i < 16; ++i) h[i] = 0.f;
#pragma unroll
      for (int ks = 0; ks < 4; ++ks) h = MFMA(a[ks], xf[ks], h);

      // relu + packed cvt: pk[2q+hh] covers C regs 4q..4q+3
      unsigned pk[8];
#pragma unroll
      for (int q = 0; q < 4; ++q) {
        pk[2*q]   = pk2(fmaxf(h[4*q+0], 0.f), fmaxf(h[4*q+1], 0.f));
        pk[2*q+1] = pk2(fmaxf(h[4*q+2], 0.f), fmaxf(h[4*q+3], 0.f));
      }

      // GEMM2: out^T += W2^T frag x h^T frag; h^T B-frag built in-register
      // via one cross-half __shfl_xor(32) pair per fragment (PROVEN R1/R3).
#pragma unroll
      for (int sub = 0; sub < 2; ++sub) {
        const int ks2 = 2 * ft + sub;
        const short8 wA = lds_read16(w2t, baseW + ks2 * 2048);
        const short8 wB = lds_read16(w2t, baseW + 512 + ks2 * 2048);
        const int qa = 2 * sub, qb = 2 * sub + 1;

        union { short8 v; unsigned u[4]; } b;
        {
          unsigned pa0 = pk[2*qa], pa1 = pk[2*qa+1];
          unsigned pb0 = pk[2*qb], pb1 = pk[2*qb+1];
          unsigned s0 = g ? pa0 : pb0, s1 = g ? pa1 : pb1;  // what partner needs
          unsigned k0 = g ? pb0 : pa0, k1 = g ? pb1 : pa1;  // what I keep
          unsigned r0 = __shfl_xor(s0, 32, 64);
          unsigned r1 = __shfl_xor(s1, 32, 64);
          b.u[0] = g ? r0 : k0; b.u[1] = g ? r1 : k1;
          b.u[2] = g ? k0 : r0; b.u[3] = g ? k1 : r1;
        }

        o0 = MFMA(wA, b.v, o0);
        o1 = MFMA(wB, b.v, o1);
      }
    }

    // ---- store out^T C-frags: 4 consecutive d per reg-quad -> float4 stores ----
#pragma unroll
    for (int dt = 0; dt < 2; ++dt) {
      const f32x16& acc = dt == 0 ? o0 : o1;
      float* po = out + (rb + m) * 64 + dt * 32 + g * 4;
#pragma unroll
      for (int q = 0; q < 4; ++q) {
        float4 s;
        s.x = acc[4*q+0]; s.y = acc[4*q+1]; s.z = acc[4*q+2]; s.w = acc[4*q+3];
        *reinterpret_cast<float4*>(po + 8 * q) = s;  // d = dt*32 + 8q + 4g + 0..3
      }
    }
  }
}

extern "C" void kernel_launch(void* const* d_in, const int* in_sizes, int n_in,
                              void* d_out, int out_size, void* d_ws, size_t ws_size,
                              hipStream_t stream) {
  const float* x  = (const float*)d_in[0];
  const float* w1 = (const float*)d_in[1];
  const float* w2 = (const float*)d_in[2];
  float* out = (float*)d_out;
  ffn_fused<<<dim3(512), dim3(768), 0, stream>>>(x, w1, w2, out);
}

// Round 18
// 64.536 us; speedup vs baseline: 1.0503x; 1.0503x over previous
//
#include <hip/hip_runtime.h>
#include <hip/hip_bf16.h>

typedef __attribute__((ext_vector_type(8))) short short8;
typedef __attribute__((ext_vector_type(16))) float f32x16;

__device__ __forceinline__ unsigned short bfbits(float f) {
  return __builtin_bit_cast(unsigned short, __float2bfloat16(f));
}

__device__ __forceinline__ short8 lds_read16(const short* p, int byteOff) {
  return *reinterpret_cast<const short8*>(reinterpret_cast<const char*>(p) + byteOff);
}

#define MFMA(a, b, c) __builtin_amdgcn_mfma_f32_32x32x16_bf16((a), (b), (c), 0, 0, 0)

// x:[524288][64] f32, w1:[8][64][256] f32, w2:[8][256][64] f32, out = x shape.
// Grid 512 x 768 threads. expert = blockIdx&7 (XCD-pinned), chunk =
// blockIdx>>3 in 0..63 owns 1024 rows = 32 tiles of 32 rows.
// Tile split across 12 waves: wv<8 -> 3 tiles, wv>=8 -> 2 tiles.
//
// R18 KEY CHANGE -- exchange-free GEMM2 via f-permutation:
// h is internal, so any f-permutation is legal if applied to BOTH W1-cols
// and W2-rows. GEMM1's C gives lane (m,g) h-rows f = r+8q+4g (C-reg 4q+r);
// GEMM2's B-operand wants lane (m,g) to supply k-slots 8g+j of each
// 16-f-slice ks2. Staging W2 chunk (ks2,g) with PHYSICAL rows
//   16ks2+4g+{0..3}, 16ks2+8+4g+{0..3}   (in that word order)
// makes the lane's own pk words [4sub..4sub+3] exactly the B-fragment:
// the entire __shfl_xor+select network (16 bpermutes + ~100 VALU/tile,
// and the longest serial link pack->bpermute->MFMA) is deleted.
// A-operand (W2^T rows d) reads the SAME chunks -> same permutation, and
// all LDS addressing is byte-identical to R15; only chunk contents move.
// (cvt_pk intrinsic reverted: R17 measured VALUBusy 26->33%, dur +2us.)
//
// Measured trail: R11 16w=67.5 -> R15 24w=65.8 (TLP saturated; all pipes
// <=26%, VALU largest). LDS layouts (R13): conflict-free, addr=base+imm:
//   w1t chunk(c=ks*2+g, f):  byte c*4096 + f*16 = W1^T[f][d=8c..8c+7]
//   w2t chunk(c2=ks2*2+g,d): byte c2*1024 + d*16 (permuted contents above)
__launch_bounds__(768, 2)
__global__ void ffn_fused(const float* __restrict__ x,
                          const float* __restrict__ w1,
                          const float* __restrict__ w2,
                          float* __restrict__ out) {
  __shared__ short w1t[4 * 2 * 256 * 8];   // 32 KB
  __shared__ short w2t[16 * 2 * 64 * 8];   // 32 KB

  const int tid  = threadIdx.x;
  const int lane = tid & 63;
  const int wv   = tid >> 6;   // wave 0..11
  const int m    = lane & 31;
  const int g    = lane >> 5;

  const int e     = blockIdx.x & 7;   // expert -> XCD pinned (weights L2-hot)
  const int chunk = blockIdx.x >> 3;  // 0..63

  const float* W1 = w1 + e * (64 * 256);
  const float* W2 = w2 + e * (256 * 64);

  // ---- stage W1 chunks (threads 0..511 only) ----
  if (tid < 512) {
    const int f  = tid & 255;
    const int cb = (tid >> 8) * 4;
#pragma unroll 2
    for (int ci = 0; ci < 4; ++ci) {
      const int c  = cb + ci;     // c = ks*2+g
      const int d0 = c * 8;
      unsigned u0, u1, u2, u3;
      {
        float a0 = W1[(d0 + 0) * 256 + f], a1 = W1[(d0 + 1) * 256 + f];
        float a2 = W1[(d0 + 2) * 256 + f], a3 = W1[(d0 + 3) * 256 + f];
        float a4 = W1[(d0 + 4) * 256 + f], a5 = W1[(d0 + 5) * 256 + f];
        float a6 = W1[(d0 + 6) * 256 + f], a7 = W1[(d0 + 7) * 256 + f];
        u0 = (unsigned)bfbits(a0) | ((unsigned)bfbits(a1) << 16);
        u1 = (unsigned)bfbits(a2) | ((unsigned)bfbits(a3) << 16);
        u2 = (unsigned)bfbits(a4) | ((unsigned)bfbits(a5) << 16);
        u3 = (unsigned)bfbits(a6) | ((unsigned)bfbits(a7) << 16);
      }
      *reinterpret_cast<uint4*>(reinterpret_cast<char*>(w1t) + c * 4096 + f * 16) =
          make_uint4(u0, u1, u2, u3);
    }
  }
  // ---- stage W2 chunks (f-PERMUTED): chunk c2 = ks2*2 + g2 holds physical
  //      rows 16ks2+4g2+{0..3} then 16ks2+8+4g2+{0..3} ----
  {
    const int d = tid & 63;
    const int r = tid >> 6;
#pragma unroll 1
    for (int ci = 0; ci < 3; ++ci) {
      const int c2 = r + 12 * ci;  // r<8: 3 chunks; r>=8: 2 chunks
      if (c2 < 32) {
        const int g2    = c2 & 1;
        const int ks2   = c2 >> 1;
        const int fbase = 16 * ks2 + 4 * g2;
        unsigned u0, u1, u2, u3;
        {
          float a0 = W2[(fbase + 0) * 64 + d], a1 = W2[(fbase + 1) * 64 + d];
          float a2 = W2[(fbase + 2) * 64 + d], a3 = W2[(fbase + 3) * 64 + d];
          float a4 = W2[(fbase + 8) * 64 + d], a5 = W2[(fbase + 9) * 64 + d];
          float a6 = W2[(fbase + 10) * 64 + d], a7 = W2[(fbase + 11) * 64 + d];
          u0 = (unsigned)bfbits(a0) | ((unsigned)bfbits(a1) << 16);
          u1 = (unsigned)bfbits(a2) | ((unsigned)bfbits(a3) << 16);
          u2 = (unsigned)bfbits(a4) | ((unsigned)bfbits(a5) << 16);
          u3 = (unsigned)bfbits(a6) | ((unsigned)bfbits(a7) << 16);
        }
        *reinterpret_cast<uint4*>(reinterpret_cast<char*>(w2t) + c2 * 1024 + d * 16) =
            make_uint4(u0, u1, u2, u3);
      }
    }
  }
  __syncthreads();  // only barrier in the kernel

  // tile range for this wave: wv<8 -> 3 tiles, wv>=8 -> 2 tiles (32 total)
  const int t0 = (wv < 8) ? 3 * wv : 24 + 2 * (wv - 8);
  const int t1 = (wv < 8) ? t0 + 3 : t0 + 2;

  const long rowBase = (long)e * 65536 + (long)chunk * 1024;

  // per-lane LDS read bases; all per-read variation is immediate/induction
  const int baseA = g * 4096 + m * 16;  // + ks*8192 + ft*512
  const int baseW = g * 1024 + m * 16;  // + ks2*2048 (+512 for d+32 row)

#pragma unroll 1
  for (int it = t0; it < t1; ++it) {
    const long rb = rowBase + it * 32;  // this wave's 32 rows this tile

    // ---- load + convert x fragments ----
    short8 xf[4];
#pragma unroll
    for (int ks = 0; ks < 4; ++ks) {
      const float* px = x + (rb + m) * 64 + ks * 16 + g * 8;
      const float4 u0 = *reinterpret_cast<const float4*>(px);
      const float4 u1 = *reinterpret_cast<const float4*>(px + 4);
      short8 v;
      v[0] = (short)bfbits(u0.x); v[1] = (short)bfbits(u0.y);
      v[2] = (short)bfbits(u0.z); v[3] = (short)bfbits(u0.w);
      v[4] = (short)bfbits(u1.x); v[5] = (short)bfbits(u1.y);
      v[6] = (short)bfbits(u1.z); v[7] = (short)bfbits(u1.w);
      xf[ks] = v;
    }

    f32x16 o0, o1;  // out^T acc per dt half
#pragma unroll
    for (int i = 0; i < 16; ++i) { o0[i] = 0.f; o1[i] = 0.f; }

#pragma unroll 1
    for (int ft = 0; ft < 8; ++ft) {
      // GEMM1: h^T tile [32f x 32m]; a-reads lane-contiguous, addr = base+imm
      short8 a[4];
#pragma unroll
      for (int ks = 0; ks < 4; ++ks)
        a[ks] = lds_read16(w1t, baseA + ks * 8192 + ft * 512);

      f32x16 h;
#pragma unroll
      for (int i = 0; i < 16; ++i) h[i] = 0.f;
#pragma unroll
      for (int ks = 0; ks < 4; ++ks) h = MFMA(a[ks], xf[ks], h);

      // relu + pack to bf16 pairs: pk[2q+hh] covers C regs 4q..4q+3
      unsigned pk[8];
#pragma unroll
      for (int q = 0; q < 4; ++q) {
        pk[2*q]   = (unsigned)bfbits(fmaxf(h[4*q+0], 0.f)) | ((unsigned)bfbits(fmaxf(h[4*q+1], 0.f)) << 16);
        pk[2*q+1] = (unsigned)bfbits(fmaxf(h[4*q+2], 0.f)) | ((unsigned)bfbits(fmaxf(h[4*q+3], 0.f)) << 16);
      }

      // GEMM2 (exchange-free): B-fragment = lane's OWN pk quads; the
      // f-permutation in the W2 chunks makes the layouts line up.
#pragma unroll
      for (int sub = 0; sub < 2; ++sub) {
        const int ks2 = 2 * ft + sub;
        const short8 wA = lds_read16(w2t, baseW + ks2 * 2048);
        const short8 wB = lds_read16(w2t, baseW + 512 + ks2 * 2048);

        union { short8 v; unsigned u[4]; } b;
        b.u[0] = pk[4 * sub + 0];
        b.u[1] = pk[4 * sub + 1];
        b.u[2] = pk[4 * sub + 2];
        b.u[3] = pk[4 * sub + 3];

        o0 = MFMA(wA, b.v, o0);
        o1 = MFMA(wB, b.v, o1);
      }
    }

    // ---- store out^T C-frags: 4 consecutive d per reg-quad -> float4 stores ----
#pragma unroll
    for (int dt = 0; dt < 2; ++dt) {
      const f32x16& acc = dt == 0 ? o0 : o1;
      float* po = out + (rb + m) * 64 + dt * 32 + g * 4;
#pragma unroll
      for (int q = 0; q < 4; ++q) {
        float4 s;
        s.x = acc[4*q+0]; s.y = acc[4*q+1]; s.z = acc[4*q+2]; s.w = acc[4*q+3];
        *reinterpret_cast<float4*>(po + 8 * q) = s;  // d = dt*32 + 8q + 4g + 0..3
      }
    }
  }
}

extern "C" void kernel_launch(void* const* d_in, const int* in_sizes, int n_in,
                              void* d_out, int out_size, void* d_ws, size_t ws_size,
                              hipStream_t stream) {
  const float* x  = (const float*)d_in[0];
  const float* w1 = (const float*)d_in[1];
  const float* w2 = (const float*)d_in[2];
  float* out = (float*)d_out;
  ffn_fused<<<dim3(512), dim3(768), 0, stream>>>(x, w1, w2, out);
}